// Round 4
// baseline (467.815 us; speedup 1.0000x reference)
//
#include <hip/hip_runtime.h>

#define RR 32
#define R3 32768
#define BATCH 8
#define CH 64
#define NPTS 100000
#define NPOINTS (BATCH * NPTS)   // 800000
#define NVOX (BATCH * R3)        // 262144
#define SCAN_BLOCKS (NVOX / 256) // 1024
#define HBLK 32                  // histogram blocks per batch
#define PPB (NPTS / HBLK)        // 3125 points per hist block
#define NTILE 1563               // ceil(100000 / 64) point tiles per batch

typedef unsigned int uint32;
typedef unsigned short uint16;

__device__ __forceinline__ uint32 f2bf(float f) {
    uint32 u = __float_as_uint(f);
    return (u + 0x7fffu + ((u >> 16) & 1u)) >> 16;   // RNE to bf16
}
__device__ __forceinline__ float bf2f(uint32 h) {
    return __uint_as_float(h << 16);
}

// ---------------------------------------------------------------------------
// K1: voxelize + LDS-privatized histogram (NO global atomics).
// 32 blocks per batch; 128 KiB LDS hist; uint4 zero/flush.
// ---------------------------------------------------------------------------
__global__ __launch_bounds__(256) void voxhist(
    const float* __restrict__ coords,  // [B, 3, N]
    uint16* __restrict__ vox,          // [NPOINTS] local voxel id (0..32767)
    uint32* __restrict__ phist,        // [B*HBLK][R3] partial histograms
    float* __restrict__ out2)          // [B, 3, N] voxel coords as float
{
    __shared__ uint32 hist[R3];        // 128 KiB

    int b   = blockIdx.x >> 5;         // 0..7
    int blk = blockIdx.x & 31;         // 0..31
    int tid = threadIdx.x;

    uint4 z4 = make_uint4(0u, 0u, 0u, 0u);
    for (int i = tid; i < R3 / 4; i += 256) ((uint4*)hist)[i] = z4;
    __syncthreads();

    int n0 = blk * PPB;
    const float* cb = coords + (size_t)b * 3 * NPTS;
    float*       o2 = out2   + (size_t)b * 3 * NPTS;

    for (int i = tid; i < PPB; i += 256) {
        int n = n0 + i;
        float fx = fminf(fmaxf(cb[n]            * 32.0f, 0.0f), 31.0f);
        float fy = fminf(fmaxf(cb[NPTS + n]     * 32.0f, 0.0f), 31.0f);
        float fz = fminf(fmaxf(cb[2 * NPTS + n] * 32.0f, 0.0f), 31.0f);
        int x = (int)rintf(fx);   // round-half-even matches jnp.round
        int y = (int)rintf(fy);
        int z = (int)rintf(fz);
        int v = x * (RR * RR) + y * RR + z;

        o2[n]            = (float)x;
        o2[NPTS + n]     = (float)y;
        o2[2 * NPTS + n] = (float)z;

        vox[(size_t)b * NPTS + n] = (uint16)v;
        atomicAdd(&hist[v], 1u);   // ds_add_u32, no global traffic
    }
    __syncthreads();

    uint4* ph = (uint4*)(phist + (size_t)(b * HBLK + blk) * R3);
    for (int i = tid; i < R3 / 4; i += 256) ph[i] = ((const uint4*)hist)[i];
}

// ---------------------------------------------------------------------------
// K2: sum the 32 partial histograms per voxel -> cnt, and per-256 block sums.
// ---------------------------------------------------------------------------
__global__ __launch_bounds__(256) void scan_hist_sums(
    const uint32* __restrict__ phist,
    uint32* __restrict__ cnt, uint32* __restrict__ bsum)
{
    __shared__ uint32 s[256];
    int t = threadIdx.x;
    int gid = blockIdx.x * 256 + t;
    int b = gid >> 15;                 // gid / R3
    int v = gid & (R3 - 1);

    const uint32* ph = phist + (size_t)b * HBLK * R3 + v;
    uint32 c = 0;
#pragma unroll
    for (int k = 0; k < HBLK; ++k) c += ph[(size_t)k * R3];
    cnt[gid] = c;

    s[t] = c;
    __syncthreads();
    for (int off = 128; off > 0; off >>= 1) {
        if (t < off) s[t] += s[t + off];
        __syncthreads();
    }
    if (t == 0) bsum[blockIdx.x] = s[0];
}

// ---------------------------------------------------------------------------
// K3: scan over the 1024 block sums (single block).
// ---------------------------------------------------------------------------
__global__ __launch_bounds__(256) void scan_bsum(uint32* __restrict__ bsum)
{
    __shared__ uint32 s[256];
    int t = threadIdx.x;
    uint32 v0 = bsum[4 * t], v1 = bsum[4 * t + 1], v2 = bsum[4 * t + 2], v3 = bsum[4 * t + 3];
    uint32 tot = v0 + v1 + v2 + v3;
    s[t] = tot;
    __syncthreads();
    for (int off = 1; off < 256; off <<= 1) {
        uint32 x = (t >= off) ? s[t - off] : 0u;
        __syncthreads();
        s[t] += x;
        __syncthreads();
    }
    uint32 excl = s[t] - tot;
    bsum[4 * t]     = excl;
    bsum[4 * t + 1] = excl + v0;
    bsum[4 * t + 2] = excl + v0 + v1;
    bsum[4 * t + 3] = excl + v0 + v1 + v2;
}

// ---------------------------------------------------------------------------
// K4: final exclusive scan -> starts[], cursor[].
// ---------------------------------------------------------------------------
__global__ __launch_bounds__(256) void scan_final(
    const uint32* __restrict__ cnt, const uint32* __restrict__ bsum,
    uint32* __restrict__ starts, uint32* __restrict__ cursor)
{
    __shared__ uint32 s[256];
    int t = threadIdx.x;
    int gid = blockIdx.x * 256 + t;
    uint32 v = cnt[gid];
    s[t] = v;
    __syncthreads();
    for (int off = 1; off < 256; off <<= 1) {
        uint32 x = (t >= off) ? s[t - off] : 0u;
        __syncthreads();
        s[t] += x;
        __syncthreads();
    }
    uint32 st = bsum[blockIdx.x] + s[t] - v;   // exclusive
    starts[gid] = st;
    cursor[gid] = st;
}

// ---------------------------------------------------------------------------
// K5: transpose feat [B,C,N] f32 -> featT [B,N,C] bf16 (coalesced both sides).
// (round-2-verified kernel; uint16 slot c holds channel c)
// ---------------------------------------------------------------------------
__global__ __launch_bounds__(256) void transpose_bf16(
    const float* __restrict__ feat,    // [B, C, N]
    uint16* __restrict__ featT)        // [B, N, C] bf16
{
    __shared__ float tile[64][65];

    int b    = blockIdx.x / NTILE;
    int t    = blockIdx.x - b * NTILE;
    int n0   = t * 64;
    int tid  = threadIdx.x;

    int i  = tid & 63;
    int cq = tid >> 6;          // 0..3
    const float* fb = feat + (size_t)b * CH * NPTS;
    int n = n0 + i;
    bool ok = (n < NPTS);
#pragma unroll
    for (int k = 0; k < 16; ++k) {
        int c = cq * 16 + k;
        float v = ok ? fb[(size_t)c * NPTS + n] : 0.0f;
        tile[c][i] = v;
    }
    __syncthreads();

    int q = tid & 7;
#pragma unroll
    for (int h = 0; h < 2; ++h) {
        int r = (tid >> 3) + 32 * h;        // 0..63
        int nr = n0 + r;
        if (nr < NPTS) {
            uint4 wv;
            wv.x = f2bf(tile[8*q+0][r]) | (f2bf(tile[8*q+1][r]) << 16);
            wv.y = f2bf(tile[8*q+2][r]) | (f2bf(tile[8*q+3][r]) << 16);
            wv.z = f2bf(tile[8*q+4][r]) | (f2bf(tile[8*q+5][r]) << 16);
            wv.w = f2bf(tile[8*q+6][r]) | (f2bf(tile[8*q+7][r]) << 16);
            ((uint4*)featT)[((size_t)b * NPTS + nr) * 8 + q] = wv;
        }
    }
}

// ---------------------------------------------------------------------------
// K6: scatter point INDICES (4 B) into voxel order. Random traffic is 32x
// smaller than scattering 128 B feature rows.
// ---------------------------------------------------------------------------
__global__ __launch_bounds__(256) void scatter_idx(
    const uint16* __restrict__ vox,
    uint32* __restrict__ cursor,
    uint32* __restrict__ order)
{
    int gid = blockIdx.x * blockDim.x + threadIdx.x;
    if (gid >= NPOINTS) return;
    int b = gid / NPTS;
    int n = gid - b * NPTS;
    uint32 g = (uint32)(b * R3 + (int)vox[gid]);
    uint32 pos = atomicAdd(&cursor[g], 1u);
    order[pos] = (uint32)n;
}

// ---------------------------------------------------------------------------
// K7: gather-reduce. Per block: 64 consecutive voxels; wave halves take
// even/odd points; featT rows gathered (128 B coalesced, L3-resident);
// counts recomputed from starts diffs. LDS transpose + coalesced write.
// ---------------------------------------------------------------------------
__global__ __launch_bounds__(256) void gather_reduce(
    const uint32* __restrict__ order,    // [NPOINTS] point idx within batch
    const uint32* __restrict__ featT,    // [B][NPTS][32] bf16x2
    const uint32* __restrict__ starts,
    float* __restrict__ out1)            // [B, C, R3]
{
    __shared__ float tile[64][65];

    int gbase = blockIdx.x * 64;       // global voxel base
    int tid = threadIdx.x;
    int w = tid >> 6, lane = tid & 63;
    int half = lane >> 5;              // 0: even points, 1: odd points
    int cp   = lane & 31;              // channel-pair index
    int b = gbase >> 15;               // gbase / R3
    const uint32* fTb = featT + (size_t)b * NPTS * 32;

    for (int k = 0; k < 16; ++k) {
        int g = gbase + w * 16 + k;
        uint32 s = starts[g];
        uint32 e = (g == NVOX - 1) ? (uint32)NPOINTS : starts[g + 1];
        float a0 = 0.0f, a1 = 0.0f;
        for (uint32 p = s + half; p < e; p += 2) {
            uint32 n = order[p];                      // broadcast in half
            uint32 d = fTb[(size_t)n * 32 + cp];      // 128 B coalesced
            a0 += bf2f(d & 0xffffu);
            a1 += bf2f(d >> 16);
        }
        a0 += __shfl_xor(a0, 32);
        a1 += __shfl_xor(a1, 32);
        if (half == 0) {
            uint32 c = e - s;
            float rcp = 1.0f / (float)(c > 1u ? c : 1u);
            int vloc = w * 16 + k;
            tile[vloc][2 * cp]     = a0 * rcp;
            tile[vloc][2 * cp + 1] = a1 * rcp;
        }
    }
    __syncthreads();

    int v0 = gbase - b * R3;
    int vv = tid & 63;
    int c0 = tid >> 6;
    float* obase = out1 + (size_t)b * CH * R3 + v0 + vv;
#pragma unroll
    for (int jj = 0; jj < 16; ++jj) {
        int c = jj * 4 + c0;
        obase[(size_t)c * R3] = tile[vv][c];
    }
}

// ---------------------------------------------------------------------------
// Fallback paths (small ws): direct atomic kernels.
// ---------------------------------------------------------------------------
__global__ __launch_bounds__(256) void accum_direct(
    const float* __restrict__ feat, const float* __restrict__ coords,
    float* __restrict__ out1, uint32* __restrict__ cnt, float* __restrict__ out2)
{
    int gid = blockIdx.x * blockDim.x + threadIdx.x;
    if (gid >= NPOINTS) return;
    int b = gid / NPTS;
    int n = gid - b * NPTS;
    const float* cb = coords + (size_t)b * 3 * NPTS + n;
    float fx = fminf(fmaxf(cb[0]        * 32.0f, 0.0f), 31.0f);
    float fy = fminf(fmaxf(cb[NPTS]     * 32.0f, 0.0f), 31.0f);
    float fz = fminf(fmaxf(cb[2 * NPTS] * 32.0f, 0.0f), 31.0f);
    int x = (int)rintf(fx), y = (int)rintf(fy), z = (int)rintf(fz);
    int v = x * (RR * RR) + y * RR + z;
    float* o2 = out2 + (size_t)b * 3 * NPTS + n;
    o2[0] = (float)x; o2[NPTS] = (float)y; o2[2 * NPTS] = (float)z;
    atomicAdd(&cnt[b * R3 + v], 1u);
    float* obase = out1 + (size_t)(b * CH) * R3 + v;
    const float* frow = feat + (size_t)(b * CH) * NPTS + n;
#pragma unroll 8
    for (int c = 0; c < CH; ++c)
        unsafeAtomicAdd(&obase[(size_t)c * R3], frow[(size_t)c * NPTS]);
}

__global__ __launch_bounds__(256) void finalize_direct(
    float* __restrict__ out1, const uint32* __restrict__ cnt)
{
    size_t gid = (size_t)blockIdx.x * blockDim.x + threadIdx.x;
    size_t total = (size_t)BATCH * CH * R3;
    if (gid >= total) return;
    int v = (int)(gid & (R3 - 1));
    int b = (int)(gid / ((size_t)CH * R3));
    uint32 ct = cnt[b * R3 + v];
    out1[gid] = out1[gid] / (float)(ct > 1u ? ct : 1u);
}

// ---------------------------------------------------------------------------
extern "C" void kernel_launch(void* const* d_in, const int* in_sizes, int n_in,
                              void* d_out, int out_size, void* d_ws, size_t ws_size,
                              hipStream_t stream)
{
    const float* feat   = (const float*)d_in[0];   // [8, 64, 100000]
    const float* coords = (const float*)d_in[1];   // [8, 3, 100000]

    float* out1 = (float*)d_out;                          // [8, 64, 32768]
    float* out2 = out1 + (size_t)BATCH * CH * R3;         // [8, 3, 100000]

    // ws layout (phist ALIASES featT: phist dead before transpose runs)
    const size_t vox_off    = 0;
    const size_t vox_bytes  = (size_t)NPOINTS * 2;                 // 1.6 MB
    const size_t cnt_off    = vox_off + ((vox_bytes + 255) & ~255ull);
    const size_t cnt_bytes  = (size_t)NVOX * 4;                    // 1 MB
    const size_t starts_off = cnt_off + ((cnt_bytes + 255) & ~255ull);
    const size_t cursor_off = starts_off + ((cnt_bytes + 255) & ~255ull);
    const size_t bsum_off   = cursor_off + ((cnt_bytes + 255) & ~255ull);
    const size_t bsum_bytes = (size_t)SCAN_BLOCKS * 4;
    const size_t order_off  = (bsum_off + bsum_bytes + 255) & ~255ull;
    const size_t order_bytes= (size_t)NPOINTS * 4;                 // 3.2 MB
    const size_t featT_off  = (order_off + order_bytes + 255) & ~255ull;
    const size_t featT_bytes= (size_t)NPOINTS * CH * 2;            // 102.4 MB
    const size_t need       = featT_off + featT_bytes;
    // phist needs B*HBLK*R3*4 = 32 MB <= featT_bytes: alias onto featT.

    const int npt_blocks = (NPOINTS + 255) / 256;   // 3125

    if (ws_size >= need) {
        char* ws = (char*)d_ws;
        uint16* vox    = (uint16*)(ws + vox_off);
        uint32* cnt    = (uint32*)(ws + cnt_off);
        uint32* starts = (uint32*)(ws + starts_off);
        uint32* cursor = (uint32*)(ws + cursor_off);
        uint32* bsum   = (uint32*)(ws + bsum_off);
        uint32* order  = (uint32*)(ws + order_off);
        uint16* featT  = (uint16*)(ws + featT_off);
        uint32* phist  = (uint32*)featT;            // alias (dead after K2)

        voxhist<<<BATCH * HBLK, 256, 0, stream>>>(coords, vox, phist, out2);
        scan_hist_sums<<<SCAN_BLOCKS, 256, 0, stream>>>(phist, cnt, bsum);
        scan_bsum<<<1, 256, 0, stream>>>(bsum);
        scan_final<<<SCAN_BLOCKS, 256, 0, stream>>>(cnt, bsum, starts, cursor);
        transpose_bf16<<<BATCH * NTILE, 256, 0, stream>>>(feat, featT);
        scatter_idx<<<npt_blocks, 256, 0, stream>>>(vox, cursor, order);
        gather_reduce<<<NVOX / 64, 256, 0, stream>>>(order, (const uint32*)featT,
                                                     starts, out1);
    } else {
        // fallback: direct atomic accumulate into d_out
        uint32* cnt = (uint32*)d_ws;
        hipMemsetAsync(out1, 0, (size_t)BATCH * CH * R3 * sizeof(float), stream);
        hipMemsetAsync(d_ws, 0, (size_t)NVOX * 4, stream);
        accum_direct<<<npt_blocks, 256, 0, stream>>>(feat, coords, out1, cnt, out2);
        size_t total = (size_t)BATCH * CH * R3;
        finalize_direct<<<(unsigned)((total + 255) / 256), 256, 0, stream>>>(out1, cnt);
    }
}